// Round 8
// baseline (451.640 us; speedup 1.0000x reference)
//
#include <hip/hip_runtime.h>

// MQCCLayer forward on MI355X.
// conv(x/mag, w) * mag == conv(x, w) (conv linear in x) -> sample L2 norm cancels.
// OUT_CHANNELS == C*F -> slice is a no-op. Remaining: depthwise 3x3 same-pad conv,
// F=2 shared unit-norm filters (cross-correlation, no flip).
//
// R6 (resubmitted: two consecutive acquisition timeouts, never ran):
// LATENCY-BOUND fix -> MAX CONCURRENCY. Evidence: R4 probe (3x waves)
// sustained 4.7 TB/s aggregate with ~52us marginal rep (~peak BW), while a
// single rep runs ~3.5 TB/s; VALU 25%, occupancy 40% -> more waves = more BW.
// Structure: thread = 2 output rows x 1 quad x 2 filters; wave = 256-col
// segment; 65536 waves (2x R3, 4x R5); ~50 VGPR; launch_bounds(256,8) pins
// 8 waves/SIMD. Per row: 1 contiguous 1KB wave load + 1 two-active-lane edge
// load; edges to lanes via shfl+cndmask. nt stores; bijective XCD swizzle.

#define BATCH 32
#define CIN   4
#define HH    512
#define WW    512
#define NF    2
#define RPT   2            // output rows per thread
#define H2    (HH / RPT)   // 256 row groups
#define NSEG  2            // 256-col segments per row
#define NXCD  8

typedef float floatx4 __attribute__((ext_vector_type(4)));

__global__ __launch_bounds__(256, 8) void mqcc_kernel(
    const float* __restrict__ x,
    const float* __restrict__ angles,
    float* __restrict__ out)
{
    // --- normalized filters (uniform -> scalar) ---
    float wf[NF][9];
#pragma unroll
    for (int f = 0; f < NF; ++f) {
        float s = 0.f;
#pragma unroll
        for (int k = 0; k < 9; ++k) { float a = angles[f * 9 + k]; s += a * a; }
        float inv = rsqrtf(s);
#pragma unroll
        for (int k = 0; k < 9; ++k) wf[f][k] = angles[f * 9 + k] * inv;
    }

    // bijective XCD swizzle: 16384 blocks, chunk 2048/XCD.
    int bid   = blockIdx.x;
    int wid   = ((bid & (NXCD - 1)) << 11) + (bid >> 3);
    int gwave = wid * 4 + (threadIdx.x >> 6);    // 65536 waves
    int lane  = threadIdx.x & 63;

    // gwave bits: h2 [0..7], seg [8], c [9..10], b [11..15]
    int h2  = gwave & (H2 - 1);
    int seg = (gwave >> 8) & (NSEG - 1);
    int c   = (gwave >> 9) & (CIN - 1);
    int b   = gwave >> 11;

    int h0      = h2 * RPT;
    int segbase = seg << 8;
    int col     = segbase + (lane << 2);
    const float* xp = x + ((size_t)(b * CIN + c) * HH) * WW;

    // --- 4 input rows (h0-1 .. h0+2): 1KB wave load + 2-lane edge load each ---
    floatx4 v[4];
    float   ev[4];                                // lane0: left edge, lane63: right edge
    int  ecol   = (lane == 0) ? (segbase - 1) : (segbase + 256);
    bool eact   = ((lane == 0) && (segbase > 0)) ||
                  ((lane == 63) && (segbase + 256 < WW));
#pragma unroll
    for (int i = 0; i < 4; ++i) {
        int ri = h0 + i - 1;
        if (ri >= 0 && ri < HH) {                 // wave-uniform (h2 uniform per wave)
            const float* row = xp + (size_t)ri * WW;
            v[i] = *(const floatx4*)(row + col);
            float e = 0.f;
            if (eact) e = row[ecol];              // <=2 active lanes
            ev[i] = e;
        } else {
            v[i] = 0.f; ev[i] = 0.f;
        }
    }

    float acc[RPT][NF][4];
#pragma unroll
    for (int j = 0; j < RPT; ++j)
#pragma unroll
        for (int f = 0; f < NF; ++f)
#pragma unroll
            for (int q = 0; q < 4; ++q) acc[j][f][q] = 0.f;

#pragma unroll
    for (int i = 0; i < 4; ++i) {
        floatx4 a = v[i];
        float l = __shfl_up(a.w, 1, 64);
        float r = __shfl_down(a.x, 1, 64);
        l = (lane == 0)  ? ev[i] : l;             // 0 at image border
        r = (lane == 63) ? ev[i] : r;
        float e[6] = { l, a.x, a.y, a.z, a.w, r };
        // input row i feeds output row j = i - kh
#pragma unroll
        for (int kh = 0; kh < 3; ++kh) {
            int j = i - kh;
            if (j >= 0 && j < RPT) {
#pragma unroll
                for (int f = 0; f < NF; ++f) {
                    float w0 = wf[f][kh * 3 + 0];
                    float w1 = wf[f][kh * 3 + 1];
                    float w2 = wf[f][kh * 3 + 2];
#pragma unroll
                    for (int q = 0; q < 4; ++q) {
                        float s = acc[j][f][q];
                        s = fmaf(w0, e[q + 0], s);
                        s = fmaf(w1, e[q + 1], s);
                        s = fmaf(w2, e[q + 2], s);
                        acc[j][f][q] = s;
                    }
                }
            }
        }
    }

    // --- epilogue: 4 nt 16B stores (1KB contiguous per wave each) ---
#pragma unroll
    for (int j = 0; j < RPT; ++j) {
#pragma unroll
        for (int f = 0; f < NF; ++f) {
            floatx4 o = { acc[j][f][0], acc[j][f][1], acc[j][f][2], acc[j][f][3] };
            float* op = out + ((((size_t)b * (CIN * NF) + (c * NF + f)) * HH + (h0 + j)) * WW + col);
            __builtin_nontemporal_store(o, (floatx4*)op);
        }
    }
}

extern "C" void kernel_launch(void* const* d_in, const int* in_sizes, int n_in,
                              void* d_out, int out_size, void* d_ws, size_t ws_size,
                              hipStream_t stream) {
    const float* x      = (const float*)d_in[0];
    const float* angles = (const float*)d_in[1];
    float* out          = (float*)d_out;

    // waves = B*C*H2*NSEG = 32*4*256*2 = 65536 -> 16384 blocks (div by 8)
    const int grid  = BATCH * CIN * H2 * NSEG / 4;
    const int block = 256;

    hipLaunchKernelGGL(mqcc_kernel, dim3(grid), dim3(block), 0, stream,
                       x, angles, out);
}

// Round 10
// 437.029 us; speedup vs baseline: 1.0334x; 1.0334x over previous
//
#include <hip/hip_runtime.h>

// MQCCLayer forward on MI355X.
// conv(x/mag, w) * mag == conv(x, w) (conv linear in x) -> sample L2 norm cancels.
// OUT_CHANNELS == C*F -> slice is a no-op. Remaining: depthwise 3x3 same-pad conv,
// F=2 shared unit-norm filters (cross-correlation, no flip).
//
// R9 (resubmitted after acquisition timeout) = R8 with ONE change:
// nontemporal -> PLAIN write-back stores.
// R8 counters: WRITE_SIZE = 524,188 KB = 2.000x the 268 MB output (FETCH clean
// at 145 MB), occupancy 81%, VALU 13%, 3.49 TB/s, 196 us. The nt write-through
// stream is amplified 2x at HBM in this config (R4 probe: same nt instruction,
// 3.002x logical = no amplification -> config-dependent). Plain stores
// allocate in L2, every out line fully covered (1KB contiguous per wave per
// store) -> no RFO, poison lines merge in-cache, one writeback per line.
// Everything else byte-identical to R8 (single-variable A/B).

#define BATCH 32
#define CIN   4
#define HH    512
#define WW    512
#define NF    2
#define RPT   2            // output rows per thread
#define H2    (HH / RPT)   // 256 row groups
#define NSEG  2            // 256-col segments per row
#define NXCD  8

typedef float floatx4 __attribute__((ext_vector_type(4)));

__global__ __launch_bounds__(256, 8) void mqcc_kernel(
    const float* __restrict__ x,
    const float* __restrict__ angles,
    float* __restrict__ out)
{
    // --- normalized filters (uniform -> scalar) ---
    float wf[NF][9];
#pragma unroll
    for (int f = 0; f < NF; ++f) {
        float s = 0.f;
#pragma unroll
        for (int k = 0; k < 9; ++k) { float a = angles[f * 9 + k]; s += a * a; }
        float inv = rsqrtf(s);
#pragma unroll
        for (int k = 0; k < 9; ++k) wf[f][k] = angles[f * 9 + k] * inv;
    }

    // bijective XCD swizzle: 16384 blocks, chunk 2048/XCD.
    int bid   = blockIdx.x;
    int wid   = ((bid & (NXCD - 1)) << 11) + (bid >> 3);
    int gwave = wid * 4 + (threadIdx.x >> 6);    // 65536 waves
    int lane  = threadIdx.x & 63;

    // gwave bits: h2 [0..7], seg [8], c [9..10], b [11..15]
    int h2  = gwave & (H2 - 1);
    int seg = (gwave >> 8) & (NSEG - 1);
    int c   = (gwave >> 9) & (CIN - 1);
    int b   = gwave >> 11;

    int h0      = h2 * RPT;
    int segbase = seg << 8;
    int col     = segbase + (lane << 2);
    const float* xp = x + ((size_t)(b * CIN + c) * HH) * WW;

    // --- 4 input rows (h0-1 .. h0+2): 1KB wave load + 2-lane edge load each ---
    floatx4 v[4];
    float   ev[4];                                // lane0: left edge, lane63: right edge
    int  ecol   = (lane == 0) ? (segbase - 1) : (segbase + 256);
    bool eact   = ((lane == 0) && (segbase > 0)) ||
                  ((lane == 63) && (segbase + 256 < WW));
#pragma unroll
    for (int i = 0; i < 4; ++i) {
        int ri = h0 + i - 1;
        if (ri >= 0 && ri < HH) {                 // wave-uniform (h2 uniform per wave)
            const float* row = xp + (size_t)ri * WW;
            v[i] = *(const floatx4*)(row + col);
            float e = 0.f;
            if (eact) e = row[ecol];              // <=2 active lanes
            ev[i] = e;
        } else {
            v[i] = 0.f; ev[i] = 0.f;
        }
    }

    float acc[RPT][NF][4];
#pragma unroll
    for (int j = 0; j < RPT; ++j)
#pragma unroll
        for (int f = 0; f < NF; ++f)
#pragma unroll
            for (int q = 0; q < 4; ++q) acc[j][f][q] = 0.f;

#pragma unroll
    for (int i = 0; i < 4; ++i) {
        floatx4 a = v[i];
        float l = __shfl_up(a.w, 1, 64);
        float r = __shfl_down(a.x, 1, 64);
        l = (lane == 0)  ? ev[i] : l;             // 0 at image border
        r = (lane == 63) ? ev[i] : r;
        float e[6] = { l, a.x, a.y, a.z, a.w, r };
        // input row i feeds output row j = i - kh
#pragma unroll
        for (int kh = 0; kh < 3; ++kh) {
            int j = i - kh;
            if (j >= 0 && j < RPT) {
#pragma unroll
                for (int f = 0; f < NF; ++f) {
                    float w0 = wf[f][kh * 3 + 0];
                    float w1 = wf[f][kh * 3 + 1];
                    float w2 = wf[f][kh * 3 + 2];
#pragma unroll
                    for (int q = 0; q < 4; ++q) {
                        float s = acc[j][f][q];
                        s = fmaf(w0, e[q + 0], s);
                        s = fmaf(w1, e[q + 1], s);
                        s = fmaf(w2, e[q + 2], s);
                        acc[j][f][q] = s;
                    }
                }
            }
        }
    }

    // --- epilogue: 4 PLAIN 16B stores (1KB contiguous per wave each) ---
#pragma unroll
    for (int j = 0; j < RPT; ++j) {
#pragma unroll
        for (int f = 0; f < NF; ++f) {
            floatx4 o = { acc[j][f][0], acc[j][f][1], acc[j][f][2], acc[j][f][3] };
            float* op = out + ((((size_t)b * (CIN * NF) + (c * NF + f)) * HH + (h0 + j)) * WW + col);
            *(floatx4*)op = o;
        }
    }
}

extern "C" void kernel_launch(void* const* d_in, const int* in_sizes, int n_in,
                              void* d_out, int out_size, void* d_ws, size_t ws_size,
                              hipStream_t stream) {
    const float* x      = (const float*)d_in[0];
    const float* angles = (const float*)d_in[1];
    float* out          = (float*)d_out;

    // waves = B*C*H2*NSEG = 32*4*256*2 = 65536 -> 16384 blocks (div by 8)
    const int grid  = BATCH * CIN * H2 * NSEG / 4;
    const int block = 256;

    hipLaunchKernelGGL(mqcc_kernel, dim3(grid), dim3(block), 0, stream,
                       x, angles, out);
}

// Round 11
// 355.256 us; speedup vs baseline: 1.2713x; 1.2302x over previous
//
#include <hip/hip_runtime.h>

// MQCCLayer forward on MI355X.
// conv(x/mag, w) * mag == conv(x, w) (conv linear in x) -> sample L2 norm cancels.
// OUT_CHANNELS == C*F -> slice is a no-op. Remaining: depthwise 3x3 same-pad conv,
// F=2 shared unit-norm filters (cross-correlation, no flip).
//
// R11 = R5 structure (best measured: ~113us) with ONE change: nt -> PLAIN stores.
// Evidence trail: WRITE amplification is 2.000x for the RPT=2 structure with
// BOTH nt (R8) and plain (R10) stores, but 1.000x/rep for the RPT=4 structure
// (R4 probe) -> amp is structural, tied to rows/thread, not store type.
// R8->R10 A/B (only store-type A/B in hand): plain beat nt 196->178.5us at
// equal traffic. So: RPT=4 (clean writes) + plain stores.
// Structure: ONE WAVE = ONE FULL 512-col ROW SPAN, 4 output rows per thread.
// Lane i owns cols [4i..4i+3] (seg A) and [256+4i..256+4i+3] (seg B): per row
// two contiguous 1KB wave loads, edges via in-wave shfl+cndmask (zero edge
// loads, zero divergent branches). 16384 waves; bijective XCD swizzle.

#define BATCH 32
#define CIN   4
#define HH    512
#define WW    512
#define NF    2
#define RPT   4            // output rows per thread (4 = the write-clean config)
#define HG    (HH / RPT)   // 128 row groups
#define NXCD  8

typedef float floatx4 __attribute__((ext_vector_type(4)));

__global__ __launch_bounds__(256) void mqcc_kernel(
    const float* __restrict__ x,
    const float* __restrict__ angles,
    float* __restrict__ out)
{
    // --- normalized filters (uniform -> scalar) ---
    float wf[NF][9];
#pragma unroll
    for (int f = 0; f < NF; ++f) {
        float s = 0.f;
#pragma unroll
        for (int k = 0; k < 9; ++k) { float a = angles[f * 9 + k]; s += a * a; }
        float inv = rsqrtf(s);
#pragma unroll
        for (int k = 0; k < 9; ++k) wf[f][k] = angles[f * 9 + k] * inv;
    }

    // bijective XCD swizzle: grid 4096, chunk 512 per XCD.
    int bid   = blockIdx.x;
    int wid   = ((bid & (NXCD - 1)) << 9) + (bid >> 3);
    int gwave = wid * 4 + (threadIdx.x >> 6);   // 16384 waves
    int lane  = threadIdx.x & 63;

    // gwave bits: hg [0..6], c [7..8], b [9..13]  (block = 4 consecutive hg)
    int hg = gwave & (HG - 1);
    int c  = (gwave >> 7) & (CIN - 1);
    int b  = gwave >> 9;

    int hbase = hg * RPT;
    int col   = lane << 2;                       // segment A base; B = col+256
    const float* xp = x + ((size_t)(b * CIN + c) * HH) * WW;

    // --- all 12 loads upfront (6 rows x 2 segments), zero-fill at v-borders ---
    floatx4 va[6], vb[6];
#pragma unroll
    for (int i = 0; i < 6; ++i) {
        int ri = hbase + i - 1;
        if (ri >= 0 && ri < HH) {                // wave-uniform
            const float* row = xp + (size_t)ri * WW;
            va[i] = *(const floatx4*)(row + col);
            vb[i] = *(const floatx4*)(row + col + 256);
        } else {
            va[i] = 0.f; vb[i] = 0.f;
        }
    }

    float accA[RPT][NF][4], accB[RPT][NF][4];
#pragma unroll
    for (int j = 0; j < RPT; ++j)
#pragma unroll
        for (int f = 0; f < NF; ++f)
#pragma unroll
            for (int q = 0; q < 4; ++q) { accA[j][f][q] = 0.f; accB[j][f][q] = 0.f; }

#pragma unroll
    for (int i = 0; i < 6; ++i) {
        floatx4 a = va[i], bq = vb[i];
        // horizontal neighbors, all in-wave (cndmask, no branches):
        float a_l = __shfl_up(a.w, 1, 64);       // lane0 junk -> col -1 = 0
        float a_r = __shfl_down(a.x, 1, 64);     // lane63 junk -> col 256
        float b_l = __shfl_up(bq.w, 1, 64);      // lane0 junk -> col 255
        float b_r = __shfl_down(bq.x, 1, 64);    // lane63 junk -> col 512 = 0
        float a255 = __shfl(a.w, 63, 64);
        float b256 = __shfl(bq.x, 0, 64);
        a_l = (lane == 0)  ? 0.f  : a_l;
        b_l = (lane == 0)  ? a255 : b_l;
        a_r = (lane == 63) ? b256 : a_r;
        b_r = (lane == 63) ? 0.f  : b_r;

        float eA[6] = { a_l, a.x, a.y, a.z, a.w, a_r };
        float eB[6] = { b_l, bq.x, bq.y, bq.z, bq.w, b_r };

        // input row i feeds output row j = i - kh
#pragma unroll
        for (int kh = 0; kh < 3; ++kh) {
            int j = i - kh;
            if (j >= 0 && j < RPT) {
#pragma unroll
                for (int f = 0; f < NF; ++f) {
                    float w0 = wf[f][kh * 3 + 0];
                    float w1 = wf[f][kh * 3 + 1];
                    float w2 = wf[f][kh * 3 + 2];
#pragma unroll
                    for (int q = 0; q < 4; ++q) {
                        float sA = accA[j][f][q];
                        sA = fmaf(w0, eA[q + 0], sA);
                        sA = fmaf(w1, eA[q + 1], sA);
                        sA = fmaf(w2, eA[q + 2], sA);
                        accA[j][f][q] = sA;
                        float sB = accB[j][f][q];
                        sB = fmaf(w0, eB[q + 0], sB);
                        sB = fmaf(w1, eB[q + 1], sB);
                        sB = fmaf(w2, eB[q + 2], sB);
                        accB[j][f][q] = sB;
                    }
                }
            }
        }
    }

    // --- epilogue: 16 PLAIN 16B stores (two contiguous 1KB spans per wave-store) ---
#pragma unroll
    for (int j = 0; j < RPT; ++j) {
#pragma unroll
        for (int f = 0; f < NF; ++f) {
            float* op = out + ((((size_t)b * (CIN * NF) + (c * NF + f)) * HH + (hbase + j)) * WW);
            floatx4 oA = { accA[j][f][0], accA[j][f][1], accA[j][f][2], accA[j][f][3] };
            floatx4 oB = { accB[j][f][0], accB[j][f][1], accB[j][f][2], accB[j][f][3] };
            *(floatx4*)(op + col)       = oA;
            *(floatx4*)(op + col + 256) = oB;
        }
    }
}

extern "C" void kernel_launch(void* const* d_in, const int* in_sizes, int n_in,
                              void* d_out, int out_size, void* d_ws, size_t ws_size,
                              hipStream_t stream) {
    const float* x      = (const float*)d_in[0];
    const float* angles = (const float*)d_in[1];
    float* out          = (float*)d_out;

    // waves = B*C*HG = 32*4*128 = 16384 -> 4096 blocks of 256 (div by 8)
    const int grid  = BATCH * CIN * HG / 4;
    const int block = 256;

    hipLaunchKernelGGL(mqcc_kernel, dim3(grid), dim3(block), 0, stream,
                       x, angles, out);
}